// Round 4
// baseline (302.358 us; speedup 1.0000x reference)
//
#include <hip/hip_runtime.h>

typedef unsigned short u16;
typedef unsigned int u32;
typedef __attribute__((ext_vector_type(8))) short short8;
typedef __attribute__((ext_vector_type(4))) float f32x4;

// ---------- helpers ----------
__device__ inline u16 f2bf(float f) {           // round-to-nearest-even fp32->bf16
  u32 x = __float_as_uint(f);
  x += 0x7fff + ((x >> 16) & 1);
  return (u16)(x >> 16);
}
__device__ inline float bf2f(u16 h) {
  return __uint_as_float(((u32)h) << 16);
}
__device__ inline void gload16(const void* g, void* l) {
  // async global->LDS, 16B per lane (global_load_lds_dwordx4)
  __builtin_amdgcn_global_load_lds((const __attribute__((address_space(1))) u32*)g,
                                   (__attribute__((address_space(3))) u32*)l, 16, 0, 0);
}

// swizzled 128x128 bf16 epilogue tile in LDS (gemm_nt modes 0/1)
__device__ inline int sg(int r) {
  return ((r >> 3) & 7) ^ (((r >> 2) & 1) << 2) ^ (((r >> 3) & 1) << 1);
}
__device__ inline int stile_off(int rl, int cl) {
  return rl * 128 + (((cl >> 3) ^ sg(rl)) << 3) + (cl & 7);
}

// ---------- fused cast fp32 -> bf16 for embd and W ----------
__global__ void cast_all(const float* __restrict__ embd, const float* __restrict__ W,
                         u16* __restrict__ embd_b, u16* __restrict__ W_b) {
  const float* src; u16* dst; size_t i;
  if (blockIdx.x < 16384) {
    src = embd; dst = embd_b;
    i = ((size_t)blockIdx.x * 256 + threadIdx.x) * 4;
  } else {
    src = W; dst = W_b;
    i = ((size_t)(blockIdx.x - 16384) * 256 + threadIdx.x) * 4;
  }
  float4 v = *(const float4*)(src + i);
  ushort4 o;
  o.x = f2bf(v.x); o.y = f2bf(v.y); o.z = f2bf(v.z); o.w = f2bf(v.w);
  *(ushort4*)(dst + i) = o;
}

// ---------- NT GEMM 128x128 (modes 0/1) ----------
#define BM 128
#define BN 128
#define BK 64

template<int MODE>
__global__ __launch_bounds__(256, 2)
void gemm_nt(const u16* __restrict__ A, const u16* __restrict__ B,
             float* __restrict__ Cf, u16* __restrict__ Cb, u16* __restrict__ CT,
             const float* __restrict__ bias, float* __restrict__ rowsum,
             int M, int N, int K, float scale, long sA, long sB, long sC)
{
  __shared__ __align__(16) char smem[32768];
  u16* As = (u16*)smem;            // BM*BK u16 = 16KB
  u16* Bs = As + BM * BK;          // BN*BK u16 = 16KB
  u16* stile = (u16*)smem;         // 128*128 swizzled (MODE 0/1)

  int z, mBase, nBase, bi = 0, bj = 0;
  if (MODE == 0) {
    z = 0;
    mBase = blockIdx.y * BM;
    nBase = blockIdx.x * BN;
  } else {
    z = blockIdx.x;                 // flat%8 == batch -> one XCD per batch
    int t = blockIdx.y, row = 0;
    const int nb = N >> 7;
    while (t >= nb - row) { t -= nb - row; ++row; }
    bi = row; bj = row + t;
    mBase = bi * BM; nBase = bj * BN;
  }

  A += (size_t)z * sA;
  B += (size_t)z * sB;
  Cb += (size_t)z * sC;
  if (MODE != 0) rowsum += (size_t)z * M;

  const int tid  = threadIdx.x;
  const int lane = tid & 63;
  const int wave = tid >> 6;
  const int wm = (wave >> 1) * 64;   // 2x2 waves of 64x64
  const int wn = (wave & 1) * 64;
  const int q = lane >> 4;
  const int r = lane & 15;
  const int rswz = r & 7;

  const int srow = tid >> 3;                       // 0..31
  const int scol = ((tid & 7) ^ (srow & 7)) * 8;   // swizzled source granule
  const int lds0 = tid * 16;

  const u16* a0 = A + (size_t)(mBase + srow) * K + scol;
  const u16* b0 = B + (size_t)(nBase + srow) * K + scol;

  f32x4 acc[4][4] = {};

  for (int k0 = 0; k0 < K; k0 += BK) {
#pragma unroll
    for (int i = 0; i < 4; ++i)
      gload16(a0 + (size_t)(32 * i) * K + k0, (char*)As + lds0 + i * 4096);
#pragma unroll
    for (int i = 0; i < 4; ++i)
      gload16(b0 + (size_t)(32 * i) * K + k0, (char*)Bs + lds0 + i * 4096);
    __syncthreads();

#pragma unroll
    for (int kk = 0; kk < 2; ++kk) {
      short8 af[4], bfr[4];
#pragma unroll
      for (int t = 0; t < 4; ++t) {
        const int go = (((kk * 4 + q) ^ rswz)) * 8;
        af[t]  = *(const short8*)(As + (wm + t * 16 + r) * BK + go);
        bfr[t] = *(const short8*)(Bs + (wn + t * 16 + r) * BK + go);
      }
#pragma unroll
      for (int mi = 0; mi < 4; ++mi)
#pragma unroll
        for (int ni = 0; ni < 4; ++ni)
          acc[mi][ni] = __builtin_amdgcn_mfma_f32_16x16x32_bf16(af[mi], bfr[ni], acc[mi][ni], 0, 0, 0);
    }
    __syncthreads();
  }

  // C/D layout: col = lane&15 (r), row = (lane>>4)*4 + reg  (q*4+reg)

  if (MODE == 0) {
    float bv[4];
#pragma unroll
    for (int ni = 0; ni < 4; ++ni) bv[ni] = bias[nBase + wn + ni * 16 + r];
#pragma unroll
    for (int mi = 0; mi < 4; ++mi)
#pragma unroll
      for (int ni = 0; ni < 4; ++ni)
#pragma unroll
        for (int reg = 0; reg < 4; ++reg) {
          int rl = wm + mi * 16 + q * 4 + reg;
          int cl = wn + ni * 16 + r;
          stile[stile_off(rl, cl)] = f2bf(acc[mi][ni][reg] + bv[ni]);
        }
    __syncthreads();
    {
      const int z1 = mBase >> 11;           // batch of this row-tile
      const int n0 = mBase & 2047;
      u16* ctb = CT + (size_t)z1 * 1024 * 2048;
#pragma unroll
      for (int rnd = 0; rnd < 8; ++rnd) {
        int idx = rnd * 256 + tid;
        int ch = idx & 15, n = idx >> 4;
        short8 v = *(const short8*)(stile + n * 128 + ((ch ^ sg(n)) << 3));
        *(short8*)(Cb + (size_t)(mBase + n) * N + nBase + ch * 8) = v;
      }
#pragma unroll
      for (int rnd = 0; rnd < 8; ++rnd) {
        int idx = rnd * 256 + tid;
        int ch = idx & 15, cc = idx >> 4;
        short8 v;
#pragma unroll
        for (int j = 0; j < 8; ++j) v[j] = (short)stile[stile_off(ch * 8 + j, cc)];
        *(short8*)(ctb + (size_t)(nBase + cc) * 2048 + n0 + ch * 8) = v;
      }
    }
  } else {
    const bool mirror = (bi != bj);
    float colacc[4] = {0.f, 0.f, 0.f, 0.f};
#pragma unroll
    for (int mi = 0; mi < 4; ++mi) {
      float rs[4] = {0.f, 0.f, 0.f, 0.f};
#pragma unroll
      for (int ni = 0; ni < 4; ++ni)
#pragma unroll
        for (int reg = 0; reg < 4; ++reg) {
          float e = __expf(acc[mi][ni][reg] * scale);
          u16 h = f2bf(e);
          float f = bf2f(h);      // rounded value for num/denom consistency
          rs[reg] += f;
          if (mirror) colacc[ni] += f;
          stile[stile_off(wm + mi * 16 + q * 4 + reg, wn + ni * 16 + r)] = h;
        }
#pragma unroll
      for (int reg = 0; reg < 4; ++reg) {
        float v = rs[reg];
        v += __shfl_xor(v, 1);
        v += __shfl_xor(v, 2);
        v += __shfl_xor(v, 4);
        v += __shfl_xor(v, 8);
        if (r == 0)
          atomicAdd(&rowsum[mBase + wm + mi * 16 + q * 4 + reg], v);
      }
    }
    if (mirror) {
#pragma unroll
      for (int ni = 0; ni < 4; ++ni) {
        float v = colacc[ni];
        v += __shfl_xor(v, 16);
        v += __shfl_xor(v, 32);
        if (q == 0)
          atomicAdd(&rowsum[nBase + wn + ni * 16 + r], v);
      }
    }
    __syncthreads();
#pragma unroll
    for (int rnd = 0; rnd < 8; ++rnd) {
      int idx = rnd * 256 + tid;
      int ch = idx & 15, n = idx >> 4;
      short8 v = *(const short8*)(stile + n * 128 + ((ch ^ sg(n)) << 3));
      *(short8*)(Cb + (size_t)(mBase + n) * N + nBase + ch * 8) = v;
    }
    if (mirror) {
#pragma unroll
      for (int rnd = 0; rnd < 8; ++rnd) {
        int idx = rnd * 256 + tid;
        int ch = idx & 15, cc = idx >> 4;
        short8 v;
#pragma unroll
        for (int j = 0; j < 8; ++j) v[j] = (short)stile[stile_off(ch * 8 + j, cc)];
        *(short8*)(Cb + (size_t)(nBase + cc) * N + mBase + ch * 8) = v;
      }
    }
  }
}

// ---------- P@cT: 256x256 tile, 8 waves, 4-buffer ring, fine phases ----------
// BK=32; LDS ring of 4 bufs x 32KB (A-tile 16KB + B-tile 16KB), total 128KB.
// Per K-tile i: 2 phases of {ds_read subtile | issue 2 gload_lds for tile i+3
// into buf (i+3)&3 == (i-1)&3 (free: tile i-1 fully read, barrier-ordered) |
// s_barrier | 16 MFMA (setprio) | s_barrier}. Counted vmcnt(8) once per tile
// (tiles i+2, i+3 in flight; never drained in-loop). m201/T3+T4+T5 structure.
#define PV_STAGE_A(f, t) do {                                           \
    const u16* _a = a0 + (size_t)(t) * 32;                              \
    char* _l = (char*)ldsm + (f) * 32768 + tid * 16;                    \
    gload16(_a, _l);                                                    \
    gload16(_a + 128 * (size_t)K, _l + 8192);                           \
  } while (0)
#define PV_STAGE_B(f, t) do {                                           \
    const u16* _b = b0 + (size_t)(t) * 32;                              \
    char* _l = (char*)ldsm + (f) * 32768 + 16384 + tid * 16;            \
    gload16(_b, _l);                                                    \
    gload16(_b + 128 * (size_t)K, _l + 8192);                           \
  } while (0)

__global__ __launch_bounds__(512, 2)
void gemm_pv8(const u16* __restrict__ A, const u16* __restrict__ B,
              float* __restrict__ Cf, const float* __restrict__ rowsum,
              int K, int Nn, long sA, long sB, long sC, int Mrs)
{
  // buf f at f*32KB: A [256][32] bf16 (16KB) then B [256][32] (16KB).
  // LDS granule (row,g) holds global granule g ^ (row&3) (source-preswizzled;
  // reads apply the same XOR) -> conflict-free ds_read_b128.
  __shared__ __align__(16) u16 ldsm[65536];

  const int z = blockIdx.x;                 // batch; flat%8==z -> XCD affinity
  const int y = blockIdx.y;
  const int mBase = (y >> 2) * 256;
  const int nBase = (y & 3) * 256;          // n fastest within batch

  A += (size_t)z * sA;
  B += (size_t)z * sB;
  Cf += (size_t)z * sC;
  rowsum += (size_t)z * Mrs;

  const int tid  = threadIdx.x;
  const int lane = tid & 63;
  const int wave = tid >> 6;
  const int wm = (wave >> 2) * 128;         // 2 M-groups
  const int wn = (wave & 3) * 64;           // 4 N-groups
  const int q = lane >> 4;
  const int r = lane & 15;
  const int gq = ((q ^ (r & 3)) << 3);      // swizzled read granule (u16)

  // staging addresses: 8KB per gload round (512 thr x 16B) = 128 rows x 64B
  const int srow = tid >> 2;                        // 0..127
  const int sgr  = ((tid & 3) ^ (srow & 3)) * 8;    // swizzled source granule
  const u16* a0 = A + (size_t)(mBase + srow) * K + sgr;
  const u16* b0 = B + (size_t)(nBase + srow) * K + sgr;

  const int NT = K >> 5;                    // 32-wide K tiles (64 here)
  const int rA = (wm + r) * 32;             // u16 offsets into A-tile
  const int rB = (wn + r) * 32;

  f32x4 acc[8][4] = {};

  // prologue: tiles 0,1,2 staged (12 loads); wait tile 0 (8 = tiles 1,2 in flight)
  PV_STAGE_A(0, 0); PV_STAGE_B(0, 0);
  PV_STAGE_A(1, 1); PV_STAGE_B(1, 1);
  PV_STAGE_A(2, 2); PV_STAGE_B(2, 2);
  asm volatile("s_waitcnt vmcnt(8)" ::: "memory");
  __builtin_amdgcn_s_barrier();

  for (int i = 0; i < NT; ++i) {
    __builtin_amdgcn_sched_barrier(0);      // nothing crosses the tile boundary
    const u16* Ab = ldsm + (i & 3) * 16384;
    const u16* Bb = Ab + 8192;
    const int f = (i + 3) & 3;

    // ---- phase A: B-frags + A-half0 reads | stage A of tile i+3 | MFMA mh0
    short8 bfr[4], af[4];
#pragma unroll
    for (int t = 0; t < 4; ++t)
      bfr[t] = *(const short8*)(Bb + rB + t * 512 + gq);
#pragma unroll
    for (int t = 0; t < 4; ++t)
      af[t] = *(const short8*)(Ab + rA + t * 512 + gq);
    if (i + 3 < NT) PV_STAGE_A(f, i + 3);
    __builtin_amdgcn_s_barrier();
    __builtin_amdgcn_sched_barrier(0);
    __builtin_amdgcn_s_setprio(1);
#pragma unroll
    for (int mi = 0; mi < 4; ++mi)
#pragma unroll
      for (int ni = 0; ni < 4; ++ni)
        acc[mi][ni] = __builtin_amdgcn_mfma_f32_16x16x32_bf16(
            af[mi], bfr[ni], acc[mi][ni], 0, 0, 0);
    __builtin_amdgcn_s_setprio(0);
    __builtin_amdgcn_s_barrier();

    // ---- phase B: A-half1 reads (bfr reused) | stage B of tile i+3 | MFMA mh1
#pragma unroll
    for (int t = 0; t < 4; ++t)
      af[t] = *(const short8*)(Ab + rA + 2048 + t * 512 + gq);
    if (i + 3 < NT) PV_STAGE_B(f, i + 3);
    if (i + 3 < NT)      asm volatile("s_waitcnt vmcnt(8)" ::: "memory");
    else if (i + 2 < NT) asm volatile("s_waitcnt vmcnt(4)" ::: "memory");
    else                 asm volatile("s_waitcnt vmcnt(0)" ::: "memory");
    __builtin_amdgcn_s_barrier();
    __builtin_amdgcn_sched_barrier(0);
    __builtin_amdgcn_s_setprio(1);
#pragma unroll
    for (int mi = 0; mi < 4; ++mi)
#pragma unroll
      for (int ni = 0; ni < 4; ++ni)
        acc[4 + mi][ni] = __builtin_amdgcn_mfma_f32_16x16x32_bf16(
            af[mi], bfr[ni], acc[4 + mi][ni], 0, 0, 0);
    __builtin_amdgcn_s_setprio(0);
    __builtin_amdgcn_s_barrier();
  }

  // epilogue: normalize + direct fp32 stores (64B segments, 4 rows/inst)
#pragma unroll
  for (int mi = 0; mi < 8; ++mi)
#pragma unroll
    for (int reg = 0; reg < 4; ++reg) {
      const int row = mBase + wm + mi * 16 + q * 4 + reg;
      const float inv = 1.0f / rowsum[row];
      float* crow = Cf + (size_t)row * Nn + nBase + wn + r;
#pragma unroll
      for (int ni = 0; ni < 4; ++ni)
        crow[ni * 16] = acc[mi][ni][reg] * inv;
    }
}

// ---------- launch ----------
// Problem constants: B=8, N=2048, E=O=1024
extern "C" void kernel_launch(void* const* d_in, const int* in_sizes, int n_in,
                              void* d_out, int out_size, void* d_ws, size_t ws_size,
                              hipStream_t stream) {
  const float* embd = (const float*)d_in[0];   // [8,2048,1024]
  const float* W    = (const float*)d_in[1];   // [1024,1024]
  const float* bias = (const float*)d_in[2];   // [1024]
  float* out = (float*)d_out;                  // [8,2048,1024] fp32

  char* ws = (char*)d_ws;
  u16* P_b    = (u16*)(ws + 0);            // 8*2048*2048*2 = 67108864
  u16* embd_b = (u16*)(ws + 0);            // 33554432 (aliases P, dead before GEMM2)
  u16* W_b    = (u16*)(ws + 33554432);     // 2097152  (aliases P, dead before GEMM2)
  u16* c_b    = (u16*)(ws + 67108864);     // 33554432
  u16* cT_b   = (u16*)(ws + 100663296);    // 33554432
  float* rowsum = (float*)(ws + 134217728);// 16384*4

  // 1) casts (fused)
  cast_all<<<17408, 256, 0, stream>>>(embd, W, embd_b, W_b);

  // 2) c = embd @ W^T + b, plus fused c^T : M=16384, N=1024, K=1024
  gemm_nt<0><<<dim3(8, 128, 1), 256, 0, stream>>>(
      embd_b, W_b, nullptr, c_b, cT_b, bias, nullptr,
      16384, 1024, 1024, 0.f, 0, 0, 0);

  // 3) rowsum = 0
  hipMemsetAsync(rowsum, 0, 16384 * sizeof(float), stream);

  // 4) P = exp(c c^T / 32) unnormalized bf16, triangular (S symmetric) + rowsums
  gemm_nt<1><<<dim3(8, 136, 1), 256, 0, stream>>>(
      c_b, c_b, nullptr, P_b, nullptr, nullptr, rowsum,
      2048, 2048, 1024, 0.03125f, 2048L * 1024, 2048L * 1024, 2048L * 2048);

  // 5) O = (P @ c) / rowsum : per batch M=2048, N=1024, K=2048; B = cT
  //    256^2 tiles, 8 waves, 4-buffer ring, fine phases, counted vmcnt
  gemm_pv8<<<dim3(8, 32, 1), 512, 0, stream>>>(
      P_b, cT_b, out, rowsum,
      2048, 1024, 2048L * 2048, 2048L * 1024, 2048L * 1024, 2048);
}

// Round 5
// 293.975 us; speedup vs baseline: 1.0285x; 1.0285x over previous
//
#include <hip/hip_runtime.h>

typedef unsigned short u16;
typedef unsigned int u32;
typedef __attribute__((ext_vector_type(8))) short short8;
typedef __attribute__((ext_vector_type(4))) float f32x4;

// ---------- helpers ----------
__device__ inline u16 f2bf(float f) {           // round-to-nearest-even fp32->bf16
  u32 x = __float_as_uint(f);
  x += 0x7fff + ((x >> 16) & 1);
  return (u16)(x >> 16);
}
__device__ inline float bf2f(u16 h) {
  return __uint_as_float(((u32)h) << 16);
}
__device__ inline u32 cvtpk(float lo, float hi) { // d[15:0]=bf16(lo) d[31:16]=bf16(hi), RNE
  u32 d;
  asm volatile("v_cvt_pk_bf16_f32 %0, %1, %2" : "=v"(d) : "v"(lo), "v"(hi));
  return d;
}
__device__ inline void gload16(const void* g, void* l) {
  // async global->LDS, 16B per lane (global_load_lds_dwordx4)
  __builtin_amdgcn_global_load_lds((const __attribute__((address_space(1))) u32*)g,
                                   (__attribute__((address_space(3))) u32*)l, 16, 0, 0);
}

// ---- column-major 128x128 bf16 epilogue tile (modes 0/1) ----
// element (row rw, col c) lives at u16 index c*128 + (( (rw>>2) ^ sxz(c) )<<2) + (rw&3).
// b64 granule = 4 consecutive rows of one column -> the 4 acc regs pack to ONE write.
// sxz is even (bit0 clear) so granule pairs stay adjacent -> b128 transpose reads legal.
// All three lane patterns (b64 write, scalar row read, b128 transpose read) are <=2-way.
__device__ inline int sxz(int c) {
  return (((c & 7) ^ ((c >> 3) & 7)) << 1);
}

// ---------- fused cast fp32 -> bf16 for embd and W ----------
__global__ void cast_all(const float* __restrict__ embd, const float* __restrict__ W,
                         u16* __restrict__ embd_b, u16* __restrict__ W_b) {
  const float* src; u16* dst; size_t i;
  if (blockIdx.x < 16384) {
    src = embd; dst = embd_b;
    i = ((size_t)blockIdx.x * 256 + threadIdx.x) * 4;
  } else {
    src = W; dst = W_b;
    i = ((size_t)(blockIdx.x - 16384) * 256 + threadIdx.x) * 4;
  }
  float4 v = *(const float4*)(src + i);
  ushort4 o;
  o.x = f2bf(v.x); o.y = f2bf(v.y); o.z = f2bf(v.z); o.w = f2bf(v.w);
  *(ushort4*)(dst + i) = o;
}

// ---------- NT GEMM: C[i,j] = sum_k A[i,k]*B[j,k], bf16 in, fp32 acc ----------
// MODE 0: + bias[col], store bf16 C AND bf16 C^T (fused transpose)   (Linear)
// MODE 1: triangular grid (S symmetric): exp(acc*scale), store tile + mirrored
//         tile, atomic rowsums. grid (batch, pair, 1) -> XCD = batch (flat%8)
// MODE 2: acc * (1/rowsum[row]), store fp32 coalesced via LDS staging (P@V)
#define BM 128
#define BN 128
#define BK 64

template<int MODE>
__global__ __launch_bounds__(256, 2)
void gemm_nt(const u16* __restrict__ A, const u16* __restrict__ B,
             float* __restrict__ Cf, u16* __restrict__ Cb, u16* __restrict__ CT,
             const float* __restrict__ bias, float* __restrict__ rowsum,
             int M, int N, int K, float scale, long sA, long sB, long sC)
{
  __shared__ __align__(16) char smem[32768];
  u16* As = (u16*)smem;            // BM*BK u16 = 16KB
  u16* Bs = As + BM * BK;          // BN*BK u16 = 16KB
  u16* stile = (u16*)smem;         // 128x128 column-major swizzled (MODE 0/1)
  float* stf = (float*)smem;       // 64*128 f32 (MODE 2)

  int z, mBase, nBase, bi = 0, bj = 0;
  if (MODE == 0) {
    z = 0;
    mBase = blockIdx.y * BM;
    nBase = blockIdx.x * BN;
  } else if (MODE == 1) {
    z = blockIdx.x;                 // flat%8 == batch -> one XCD per batch
    int t = blockIdx.y, row = 0;
    const int nb = N >> 7;
    while (t >= nb - row) { t -= nb - row; ++row; }
    bi = row; bj = row + t;
    mBase = bi * BM; nBase = bj * BN;
  } else {
    z = blockIdx.x;                 // flat%8 == batch
    nBase = (blockIdx.y & 7) * BN;  // n fastest within batch -> A-row-tile reuse
    mBase = (blockIdx.y >> 3) * BM;
  }

  A += (size_t)z * sA;
  B += (size_t)z * sB;
  if (MODE == 2) Cf += (size_t)z * sC; else Cb += (size_t)z * sC;
  if (MODE != 0) rowsum += (size_t)z * M;

  const int tid  = threadIdx.x;
  const int lane = tid & 63;
  const int wave = tid >> 6;
  const int wm = (wave >> 1) * 64;   // 2x2 waves of 64x64
  const int wn = (wave & 1) * 64;
  const int q = lane >> 4;
  const int r = lane & 15;
  const int rswz = r & 7;

  const int srow = tid >> 3;                       // 0..31
  const int scol = ((tid & 7) ^ (srow & 7)) * 8;   // swizzled source granule
  const int lds0 = tid * 16;

  const u16* a0 = A + (size_t)(mBase + srow) * K + scol;
  const u16* b0 = B + (size_t)(nBase + srow) * K + scol;

  f32x4 acc[4][4] = {};

  for (int k0 = 0; k0 < K; k0 += BK) {
#pragma unroll
    for (int i = 0; i < 4; ++i)
      gload16(a0 + (size_t)(32 * i) * K + k0, (char*)As + lds0 + i * 4096);
#pragma unroll
    for (int i = 0; i < 4; ++i)
      gload16(b0 + (size_t)(32 * i) * K + k0, (char*)Bs + lds0 + i * 4096);
    __syncthreads();

#pragma unroll
    for (int kk = 0; kk < 2; ++kk) {
      short8 af[4], bfr[4];
#pragma unroll
      for (int t = 0; t < 4; ++t) {
        const int go = (((kk * 4 + q) ^ rswz)) * 8;
        af[t]  = *(const short8*)(As + (wm + t * 16 + r) * BK + go);
        bfr[t] = *(const short8*)(Bs + (wn + t * 16 + r) * BK + go);
      }
#pragma unroll
      for (int mi = 0; mi < 4; ++mi)
#pragma unroll
        for (int ni = 0; ni < 4; ++ni)
          acc[mi][ni] = __builtin_amdgcn_mfma_f32_16x16x32_bf16(af[mi], bfr[ni], acc[mi][ni], 0, 0, 0);
    }
    __syncthreads();
  }

  // C/D layout: col = lane&15 (r), row = (lane>>4)*4 + reg  (q*4+reg)

  if (MODE == 0) {
    float bv[4];
#pragma unroll
    for (int ni = 0; ni < 4; ++ni) bv[ni] = bias[nBase + wn + ni * 16 + r];
    // epilogue write: one b64 per (mi,ni) = 4 rows x 1 col, cvt_pk packed
#pragma unroll
    for (int mi = 0; mi < 4; ++mi) {
      const int m8 = ((wm + mi * 16) >> 2) + q;
#pragma unroll
      for (int ni = 0; ni < 4; ++ni) {
        const int c = wn + ni * 16 + r;
        u32 p0 = cvtpk(acc[mi][ni][0] + bv[ni], acc[mi][ni][1] + bv[ni]);
        u32 p1 = cvtpk(acc[mi][ni][2] + bv[ni], acc[mi][ni][3] + bv[ni]);
        u32* dst = (u32*)(stile + c * 128 + ((m8 ^ sxz(c)) << 2));
        dst[0] = p0; dst[1] = p1;
      }
    }
    __syncthreads();
    {
      const int z1 = mBase >> 11;           // batch of this row-tile
      const int n0 = mBase & 2047;
      u16* ctb = CT + (size_t)z1 * 1024 * 2048;
      // c write: row n = col-strided scalar reads (swizzle-spread), coalesced stores
#pragma unroll
      for (int rnd = 0; rnd < 8; ++rnd) {
        int idx = rnd * 256 + tid;
        int ch = idx & 15, n = idx >> 4;
        const int m8 = n >> 2, lo2 = n & 3;
        short8 v;
#pragma unroll
        for (int j = 0; j < 8; ++j) {
          int c = ch * 8 + j;
          v[j] = (short)stile[c * 128 + ((m8 ^ sxz(c)) << 2) + lo2];
        }
        *(short8*)(Cb + (size_t)(mBase + n) * N + nBase + ch * 8) = v;
      }
      // cT write: contiguous b128 reads of stileT columns, coalesced stores
#pragma unroll
      for (int rnd = 0; rnd < 8; ++rnd) {
        int idx = rnd * 256 + tid;
        int ch = idx & 15, cc = idx >> 4;
        short8 v = *(const short8*)(stile + cc * 128 + (((2 * ch) ^ sxz(cc)) << 2));
        *(short8*)(ctb + (size_t)(nBase + cc) * 2048 + n0 + ch * 8) = v;
      }
    }
  } else if (MODE == 1) {
    const bool mirror = (bi != bj);
    float colacc[4] = {0.f, 0.f, 0.f, 0.f};
#pragma unroll
    for (int mi = 0; mi < 4; ++mi) {
      const int m8 = ((wm + mi * 16) >> 2) + q;
      float rs[4] = {0.f, 0.f, 0.f, 0.f};
#pragma unroll
      for (int ni = 0; ni < 4; ++ni) {
        const int c = wn + ni * 16 + r;
        u32 p0 = cvtpk(__expf(acc[mi][ni][0] * scale), __expf(acc[mi][ni][1] * scale));
        u32 p1 = cvtpk(__expf(acc[mi][ni][2] * scale), __expf(acc[mi][ni][3] * scale));
        // rounded values for num/denom consistency
        float f0 = __uint_as_float(p0 << 16);
        float f1 = __uint_as_float(p0 & 0xffff0000u);
        float f2 = __uint_as_float(p1 << 16);
        float f3 = __uint_as_float(p1 & 0xffff0000u);
        rs[0] += f0; rs[1] += f1; rs[2] += f2; rs[3] += f3;
        if (mirror) colacc[ni] += (f0 + f1) + (f2 + f3);
        u32* dst = (u32*)(stile + c * 128 + ((m8 ^ sxz(c)) << 2));
        dst[0] = p0; dst[1] = p1;
      }
      // direct rowsums: reduce over r (cols) within q-group
#pragma unroll
      for (int reg = 0; reg < 4; ++reg) {
        float v = rs[reg];
        v += __shfl_xor(v, 1);
        v += __shfl_xor(v, 2);
        v += __shfl_xor(v, 4);
        v += __shfl_xor(v, 8);
        if (r == 0)
          atomicAdd(&rowsum[mBase + wm + mi * 16 + q * 4 + reg], v);
      }
    }
    if (mirror) {
      // mirror rowsums = column sums: reduce over q (rows)
#pragma unroll
      for (int ni = 0; ni < 4; ++ni) {
        float v = colacc[ni];
        v += __shfl_xor(v, 16);
        v += __shfl_xor(v, 32);
        if (q == 0)
          atomicAdd(&rowsum[nBase + wn + ni * 16 + r], v);
      }
    }
    __syncthreads();
    // direct tile write: scalar col-strided reads, coalesced row stores
#pragma unroll
    for (int rnd = 0; rnd < 8; ++rnd) {
      int idx = rnd * 256 + tid;
      int ch = idx & 15, n = idx >> 4;
      const int m8 = n >> 2, lo2 = n & 3;
      short8 v;
#pragma unroll
      for (int j = 0; j < 8; ++j) {
        int c = ch * 8 + j;
        v[j] = (short)stile[c * 128 + ((m8 ^ sxz(c)) << 2) + lo2];
      }
      *(short8*)(Cb + (size_t)(mBase + n) * N + nBase + ch * 8) = v;
    }
    if (mirror) {
      // mirrored tile write: contiguous b128 column reads, coalesced stores
#pragma unroll
      for (int rnd = 0; rnd < 8; ++rnd) {
        int idx = rnd * 256 + tid;
        int ch = idx & 15, cc = idx >> 4;
        short8 v = *(const short8*)(stile + cc * 128 + (((2 * ch) ^ sxz(cc)) << 2));
        *(short8*)(Cb + (size_t)(nBase + cc) * N + mBase + ch * 8) = v;
      }
    }
  } else {
    // MODE 2: normalize + fp32 store, staged through LDS in two 64-row phases
#pragma unroll
    for (int p = 0; p < 2; ++p) {
      if ((wave >> 1) == p) {
#pragma unroll
        for (int mi = 0; mi < 4; ++mi)
#pragma unroll
          for (int reg = 0; reg < 4; ++reg) {
            int lr = mi * 16 + q * 4 + reg;
            float inv = 1.0f / rowsum[mBase + wm + lr];
#pragma unroll
            for (int ni = 0; ni < 4; ++ni)
              stf[lr * 128 + wn + ni * 16 + r] = acc[mi][ni][reg] * inv;
          }
      }
      __syncthreads();
#pragma unroll
      for (int rnd = 0; rnd < 8; ++rnd) {
        int idx = rnd * 256 + tid;
        int n = idx >> 5, ch = idx & 31;
        float4 v = *(const float4*)(stf + n * 128 + ch * 4);
        *(float4*)(Cf + (size_t)(mBase + p * 64 + n) * N + nBase + ch * 4) = v;
      }
      __syncthreads();
    }
  }
}

// ---------- launch ----------
// Problem constants: B=8, N=2048, E=O=1024
extern "C" void kernel_launch(void* const* d_in, const int* in_sizes, int n_in,
                              void* d_out, int out_size, void* d_ws, size_t ws_size,
                              hipStream_t stream) {
  const float* embd = (const float*)d_in[0];   // [8,2048,1024]
  const float* W    = (const float*)d_in[1];   // [1024,1024]
  const float* bias = (const float*)d_in[2];   // [1024]
  float* out = (float*)d_out;                  // [8,2048,1024] fp32

  char* ws = (char*)d_ws;
  u16* P_b    = (u16*)(ws + 0);            // 8*2048*2048*2 = 67108864
  u16* embd_b = (u16*)(ws + 0);            // 33554432 (aliases P, dead before GEMM2)
  u16* W_b    = (u16*)(ws + 33554432);     // 2097152  (aliases P, dead before GEMM2)
  u16* c_b    = (u16*)(ws + 67108864);     // 33554432
  u16* cT_b   = (u16*)(ws + 100663296);    // 33554432
  float* rowsum = (float*)(ws + 134217728);// 16384*4

  // 1) casts (fused)
  cast_all<<<17408, 256, 0, stream>>>(embd, W, embd_b, W_b);

  // 2) c = embd @ W^T + b, plus fused c^T : M=16384, N=1024, K=1024
  gemm_nt<0><<<dim3(8, 128, 1), 256, 0, stream>>>(
      embd_b, W_b, nullptr, c_b, cT_b, bias, nullptr,
      16384, 1024, 1024, 0.f, 0, 0, 0);

  // 3) rowsum = 0
  hipMemsetAsync(rowsum, 0, 16384 * sizeof(float), stream);

  // 4) P = exp(c c^T / 32) unnormalized bf16, triangular (S symmetric) + rowsums
  gemm_nt<1><<<dim3(8, 136, 1), 256, 0, stream>>>(
      c_b, c_b, nullptr, P_b, nullptr, nullptr, rowsum,
      2048, 2048, 1024, 0.03125f, 2048L * 1024, 2048L * 1024, 2048L * 2048);

  // 5) O = (P @ c) / rowsum : per batch M=2048, N=1024, K=2048; B = cT
  gemm_nt<2><<<dim3(8, 128, 1), 256, 0, stream>>>(
      P_b, cT_b, out, nullptr, nullptr, nullptr, rowsum,
      2048, 1024, 2048, 0.f, 2048L * 2048, 2048L * 1024, 2048L * 1024);
}

// Round 7
// 272.354 us; speedup vs baseline: 1.1102x; 1.0794x over previous
//
#include <hip/hip_runtime.h>

typedef unsigned short u16;
typedef unsigned int u32;
typedef __attribute__((ext_vector_type(8))) short short8;
typedef __attribute__((ext_vector_type(4))) float f32x4;

// ---------- helpers ----------
__device__ inline u16 f2bf(float f) {           // round-to-nearest-even fp32->bf16
  u32 x = __float_as_uint(f);
  x += 0x7fff + ((x >> 16) & 1);
  return (u16)(x >> 16);
}
__device__ inline float bf2f(u16 h) {
  return __uint_as_float(((u32)h) << 16);
}
__device__ inline u32 cvtpk(float lo, float hi) { // d[15:0]=bf16(lo) d[31:16]=bf16(hi), RNE
  u32 d;
  asm volatile("v_cvt_pk_bf16_f32 %0, %1, %2" : "=v"(d) : "v"(lo), "v"(hi));
  return d;
}
__device__ inline void gload16(const void* g, void* l) {
  // async global->LDS, 16B per lane (global_load_lds_dwordx4)
  __builtin_amdgcn_global_load_lds((const __attribute__((address_space(1))) u32*)g,
                                   (__attribute__((address_space(3))) u32*)l, 16, 0, 0);
}

// ---- column-major 128x128 bf16 epilogue tile (modes 0/1) ----
// element (row rw, col c) lives at u16 index c*128 + (((rw>>2) ^ sxz(c))<<2) + (rw&3).
// b64 granule = 4 consecutive rows of one column -> the 4 acc regs pack to ONE write.
// sxz is even (bit0 clear) so granule pairs stay adjacent -> b128 transpose reads legal.
// All three lane patterns (b64 write, scalar row read, b128 transpose read) are <=2-way.
__device__ inline int sxz(int c) {
  return (((c & 7) ^ ((c >> 3) & 7)) << 1);
}

// ---------- fused cast fp32 -> bf16 for embd and W, + rowsum zero ----------
__global__ void cast_all(const float* __restrict__ embd, const float* __restrict__ W,
                         u16* __restrict__ embd_b, u16* __restrict__ W_b,
                         float* __restrict__ rowsum) {
  if (blockIdx.x >= 17408) {        // 64 trailing blocks: zero rowsum[16384]
    rowsum[(size_t)(blockIdx.x - 17408) * 256 + threadIdx.x] = 0.f;
    return;
  }
  const float* src; u16* dst; size_t i;
  if (blockIdx.x < 16384) {
    src = embd; dst = embd_b;
    i = ((size_t)blockIdx.x * 256 + threadIdx.x) * 4;
  } else {
    src = W; dst = W_b;
    i = ((size_t)(blockIdx.x - 16384) * 256 + threadIdx.x) * 4;
  }
  float4 v = *(const float4*)(src + i);
  ushort4 o;
  o.x = f2bf(v.x); o.y = f2bf(v.y); o.z = f2bf(v.z); o.w = f2bf(v.w);
  *(ushort4*)(dst + i) = o;
}

// ---------- NT GEMM: C[i,j] = sum_k A[i,k]*B[j,k], bf16 in, fp32 acc ----------
// MODE 0: + bias[col], store bf16 C AND bf16 C^T (fused transpose)   (Linear)
//         grid (8, 128): m-tile = x + 8*(y>>3), n-tile = y&7 -> XCD (flat%8 = x)
//         owns m-panels = x mod 8: A-panels read once from HBM, 7x from own L2;
//         L2 working set ~2MB A + 2MB W.
// MODE 1: triangular grid (S symmetric): exp(acc*scale), store tile + mirrored
//         tile, atomic rowsums. grid (batch, pair, 1) -> XCD = batch (flat%8)
// MODE 2: acc * (1/rowsum[row]), store fp32 coalesced via LDS staging (P@V)
#define BM 128
#define BN 128
#define BK 64

template<int MODE>
__global__ __launch_bounds__(256, 2)
void gemm_nt(const u16* __restrict__ A, const u16* __restrict__ B,
             float* __restrict__ Cf, u16* __restrict__ Cb, u16* __restrict__ CT,
             const float* __restrict__ bias, float* __restrict__ rowsum,
             int M, int N, int K, float scale, long sA, long sB, long sC)
{
  __shared__ __align__(16) char smem[32768];
  u16* As = (u16*)smem;            // BM*BK u16 = 16KB
  u16* Bs = As + BM * BK;          // BN*BK u16 = 16KB
  u16* stile = (u16*)smem;         // 128x128 column-major swizzled (MODE 0/1)
  float* stf = (float*)smem;       // 64*128 f32 (MODE 2)

  int z, mBase, nBase, bi = 0, bj = 0;
  if (MODE == 0) {
    z = 0;
    mBase = (blockIdx.x + 8 * (blockIdx.y >> 3)) * BM;   // XCD-local m-panels
    nBase = (blockIdx.y & 7) * BN;
  } else if (MODE == 1) {
    z = blockIdx.x;                 // flat%8 == batch -> one XCD per batch
    int t = blockIdx.y, row = 0;
    const int nb = N >> 7;
    while (t >= nb - row) { t -= nb - row; ++row; }
    bi = row; bj = row + t;
    mBase = bi * BM; nBase = bj * BN;
  } else {
    z = blockIdx.x;                 // flat%8 == batch
    nBase = (blockIdx.y & 7) * BN;  // n fastest within batch -> A-row-tile reuse
    mBase = (blockIdx.y >> 3) * BM;
  }

  A += (size_t)z * sA;
  B += (size_t)z * sB;
  if (MODE == 2) Cf += (size_t)z * sC; else Cb += (size_t)z * sC;
  if (MODE != 0) rowsum += (size_t)z * M;

  const int tid  = threadIdx.x;
  const int lane = tid & 63;
  const int wave = tid >> 6;
  const int wm = (wave >> 1) * 64;   // 2x2 waves of 64x64
  const int wn = (wave & 1) * 64;
  const int q = lane >> 4;
  const int r = lane & 15;
  const int rswz = r & 7;

  const int srow = tid >> 3;                       // 0..31
  const int scol = ((tid & 7) ^ (srow & 7)) * 8;   // swizzled source granule
  const int lds0 = tid * 16;

  const u16* a0 = A + (size_t)(mBase + srow) * K + scol;
  const u16* b0 = B + (size_t)(nBase + srow) * K + scol;

  f32x4 acc[4][4] = {};

  for (int k0 = 0; k0 < K; k0 += BK) {
#pragma unroll
    for (int i = 0; i < 4; ++i)
      gload16(a0 + (size_t)(32 * i) * K + k0, (char*)As + lds0 + i * 4096);
#pragma unroll
    for (int i = 0; i < 4; ++i)
      gload16(b0 + (size_t)(32 * i) * K + k0, (char*)Bs + lds0 + i * 4096);
    __syncthreads();

#pragma unroll
    for (int kk = 0; kk < 2; ++kk) {
      short8 af[4], bfr[4];
#pragma unroll
      for (int t = 0; t < 4; ++t) {
        const int go = (((kk * 4 + q) ^ rswz)) * 8;
        af[t]  = *(const short8*)(As + (wm + t * 16 + r) * BK + go);
        bfr[t] = *(const short8*)(Bs + (wn + t * 16 + r) * BK + go);
      }
#pragma unroll
      for (int mi = 0; mi < 4; ++mi)
#pragma unroll
        for (int ni = 0; ni < 4; ++ni)
          acc[mi][ni] = __builtin_amdgcn_mfma_f32_16x16x32_bf16(af[mi], bfr[ni], acc[mi][ni], 0, 0, 0);
    }
    __syncthreads();
  }

  // C/D layout: col = lane&15 (r), row = (lane>>4)*4 + reg  (q*4+reg)

  if (MODE == 0) {
    float bv[4];
#pragma unroll
    for (int ni = 0; ni < 4; ++ni) bv[ni] = bias[nBase + wn + ni * 16 + r];
    // epilogue write: one b64 per (mi,ni) = 4 rows x 1 col, cvt_pk packed
#pragma unroll
    for (int mi = 0; mi < 4; ++mi) {
      const int m8 = ((wm + mi * 16) >> 2) + q;
#pragma unroll
      for (int ni = 0; ni < 4; ++ni) {
        const int c = wn + ni * 16 + r;
        u32 p0 = cvtpk(acc[mi][ni][0] + bv[ni], acc[mi][ni][1] + bv[ni]);
        u32 p1 = cvtpk(acc[mi][ni][2] + bv[ni], acc[mi][ni][3] + bv[ni]);
        u32* dst = (u32*)(stile + c * 128 + ((m8 ^ sxz(c)) << 2));
        dst[0] = p0; dst[1] = p1;
      }
    }
    __syncthreads();
    {
      const int z1 = mBase >> 11;           // batch of this row-tile
      const int n0 = mBase & 2047;
      u16* ctb = CT + (size_t)z1 * 1024 * 2048;
      // c write: row n = col-strided scalar reads (swizzle-spread), coalesced stores
#pragma unroll
      for (int rnd = 0; rnd < 8; ++rnd) {
        int idx = rnd * 256 + tid;
        int ch = idx & 15, n = idx >> 4;
        const int m8 = n >> 2, lo2 = n & 3;
        short8 v;
#pragma unroll
        for (int j = 0; j < 8; ++j) {
          int c = ch * 8 + j;
          v[j] = (short)stile[c * 128 + ((m8 ^ sxz(c)) << 2) + lo2];
        }
        *(short8*)(Cb + (size_t)(mBase + n) * N + nBase + ch * 8) = v;
      }
      // cT write: contiguous b128 reads of stileT columns, coalesced stores
#pragma unroll
      for (int rnd = 0; rnd < 8; ++rnd) {
        int idx = rnd * 256 + tid;
        int ch = idx & 15, cc = idx >> 4;
        short8 v = *(const short8*)(stile + cc * 128 + (((2 * ch) ^ sxz(cc)) << 2));
        *(short8*)(ctb + (size_t)(nBase + cc) * 2048 + n0 + ch * 8) = v;
      }
    }
  } else if (MODE == 1) {
    const bool mirror = (bi != bj);
    float colacc[4] = {0.f, 0.f, 0.f, 0.f};
#pragma unroll
    for (int mi = 0; mi < 4; ++mi) {
      const int m8 = ((wm + mi * 16) >> 2) + q;
      float rs[4] = {0.f, 0.f, 0.f, 0.f};
#pragma unroll
      for (int ni = 0; ni < 4; ++ni) {
        const int c = wn + ni * 16 + r;
        u32 p0 = cvtpk(__expf(acc[mi][ni][0] * scale), __expf(acc[mi][ni][1] * scale));
        u32 p1 = cvtpk(__expf(acc[mi][ni][2] * scale), __expf(acc[mi][ni][3] * scale));
        // rounded values for num/denom consistency
        float f0 = __uint_as_float(p0 << 16);
        float f1 = __uint_as_float(p0 & 0xffff0000u);
        float f2 = __uint_as_float(p1 << 16);
        float f3 = __uint_as_float(p1 & 0xffff0000u);
        rs[0] += f0; rs[1] += f1; rs[2] += f2; rs[3] += f3;
        if (mirror) colacc[ni] += (f0 + f1) + (f2 + f3);
        u32* dst = (u32*)(stile + c * 128 + ((m8 ^ sxz(c)) << 2));
        dst[0] = p0; dst[1] = p1;
      }
      // direct rowsums: reduce over r (cols) within q-group
#pragma unroll
      for (int reg = 0; reg < 4; ++reg) {
        float v = rs[reg];
        v += __shfl_xor(v, 1);
        v += __shfl_xor(v, 2);
        v += __shfl_xor(v, 4);
        v += __shfl_xor(v, 8);
        if (r == 0)
          atomicAdd(&rowsum[mBase + wm + mi * 16 + q * 4 + reg], v);
      }
    }
    if (mirror) {
      // mirror rowsums = column sums: reduce over q (rows)
#pragma unroll
      for (int ni = 0; ni < 4; ++ni) {
        float v = colacc[ni];
        v += __shfl_xor(v, 16);
        v += __shfl_xor(v, 32);
        if (q == 0)
          atomicAdd(&rowsum[nBase + wn + ni * 16 + r], v);
      }
    }
    __syncthreads();
    // direct tile write: scalar col-strided reads, coalesced row stores
#pragma unroll
    for (int rnd = 0; rnd < 8; ++rnd) {
      int idx = rnd * 256 + tid;
      int ch = idx & 15, n = idx >> 4;
      const int m8 = n >> 2, lo2 = n & 3;
      short8 v;
#pragma unroll
      for (int j = 0; j < 8; ++j) {
        int c = ch * 8 + j;
        v[j] = (short)stile[c * 128 + ((m8 ^ sxz(c)) << 2) + lo2];
      }
      *(short8*)(Cb + (size_t)(mBase + n) * N + nBase + ch * 8) = v;
    }
    if (mirror) {
      // mirrored tile write: contiguous b128 column reads, coalesced stores
#pragma unroll
      for (int rnd = 0; rnd < 8; ++rnd) {
        int idx = rnd * 256 + tid;
        int ch = idx & 15, cc = idx >> 4;
        short8 v = *(const short8*)(stile + cc * 128 + (((2 * ch) ^ sxz(cc)) << 2));
        *(short8*)(Cb + (size_t)(nBase + cc) * N + mBase + ch * 8) = v;
      }
    }
  } else {
    // MODE 2: normalize + fp32 store, staged through LDS in two 64-row phases
#pragma unroll
    for (int p = 0; p < 2; ++p) {
      if ((wave >> 1) == p) {
#pragma unroll
        for (int mi = 0; mi < 4; ++mi)
#pragma unroll
          for (int reg = 0; reg < 4; ++reg) {
            int lr = mi * 16 + q * 4 + reg;
            float inv = 1.0f / rowsum[mBase + wm + lr];
#pragma unroll
            for (int ni = 0; ni < 4; ++ni)
              stf[lr * 128 + wn + ni * 16 + r] = acc[mi][ni][reg] * inv;
          }
      }
      __syncthreads();
#pragma unroll
      for (int rnd = 0; rnd < 8; ++rnd) {
        int idx = rnd * 256 + tid;
        int n = idx >> 5, ch = idx & 31;
        float4 v = *(const float4*)(stf + n * 128 + ch * 4);
        *(float4*)(Cf + (size_t)(mBase + p * 64 + n) * N + nBase + ch * 4) = v;
      }
      __syncthreads();
    }
  }
}

// ---------- launch ----------
// Problem constants: B=8, N=2048, E=O=1024
extern "C" void kernel_launch(void* const* d_in, const int* in_sizes, int n_in,
                              void* d_out, int out_size, void* d_ws, size_t ws_size,
                              hipStream_t stream) {
  const float* embd = (const float*)d_in[0];   // [8,2048,1024]
  const float* W    = (const float*)d_in[1];   // [1024,1024]
  const float* bias = (const float*)d_in[2];   // [1024]
  float* out = (float*)d_out;                  // [8,2048,1024] fp32

  char* ws = (char*)d_ws;
  u16* P_b    = (u16*)(ws + 0);            // 8*2048*2048*2 = 67108864
  u16* embd_b = (u16*)(ws + 0);            // 33554432 (aliases P, dead before GEMM2)
  u16* W_b    = (u16*)(ws + 33554432);     // 2097152  (aliases P, dead before GEMM2)
  u16* c_b    = (u16*)(ws + 67108864);     // 33554432
  u16* cT_b   = (u16*)(ws + 100663296);    // 33554432
  float* rowsum = (float*)(ws + 134217728);// 16384*4

  // 1) casts (fused) + rowsum zero (last 64 blocks)
  cast_all<<<17472, 256, 0, stream>>>(embd, W, embd_b, W_b, rowsum);

  // 2) c = embd @ W^T + b, plus fused c^T : M=16384, N=1024, K=1024
  gemm_nt<0><<<dim3(8, 128, 1), 256, 0, stream>>>(
      embd_b, W_b, nullptr, c_b, cT_b, bias, nullptr,
      16384, 1024, 1024, 0.f, 0, 0, 0);

  // 3) P = exp(c c^T / 32) unnormalized bf16, triangular (S symmetric) + rowsums
  gemm_nt<1><<<dim3(8, 136, 1), 256, 0, stream>>>(
      c_b, c_b, nullptr, P_b, nullptr, nullptr, rowsum,
      2048, 2048, 1024, 0.03125f, 2048L * 1024, 2048L * 1024, 2048L * 2048);

  // 4) O = (P @ c) / rowsum : per batch M=2048, N=1024, K=2048; B = cT
  gemm_nt<2><<<dim3(8, 128, 1), 256, 0, stream>>>(
      P_b, cT_b, out, nullptr, nullptr, nullptr, rowsum,
      2048, 1024, 2048, 0.f, 2048L * 2048, 2048L * 1024, 2048L * 1024);
}